// Round 8
// baseline (174.860 us; speedup 1.0000x reference)
//
#include <hip/hip_runtime.h>
#include <stdint.h>
#include <math.h>

// Problem constants (fixed by the reference's setup_inputs)
#define N_BATCH 8
#define A_ELEMS 500000          // anchors per batch
#define TOPK    2000
#define NBINS   2048            // 11-bit histogram (exact-fallback path only)
#define CAP     8192            // cand capacity (normal path cnt ~2330; fallback <=4500)
#define BCAP2   128             // per-scan-block private cap (expected ~18 +- 4)
#define SBLK    128             // scan blocks per batch
#define SEG     32              // key segments (SEG*SEGK = CAP)
#define SEGK    256             // keys per segment
#define GRP     8               // candidate groups of 1024 (GRP*1024 = CAP)
#define BBOX_CLIP 4.135166556742356f  // log(1000/16)

// Monotone map float -> uint32 (ascending). Larger u <=> larger float.
__device__ __forceinline__ uint32_t f2sortable(float f) {
    uint32_t b = __float_as_uint(f);
    return (b & 0x80000000u) ? ~b : (b | 0x80000000u);
}

// ---------------- pass 1: speculative threshold compact (hot path) ----------------
// T0 = sortable(2.60): per-batch count above T0 ~2330 +- 48 for N(0,1) scores
// (>= TOPK by 6.9 sigma; exact fallback in check_kernel covers failure anyway).
// Pure streaming 16 MB read; candidates staged via one LDS counter into a
// PRIVATE per-block list (no global atomics, no pre-zero, ~150 B writes/block).
// key = (sortable<<32)|~idx: key desc == score desc, index asc (exact
// jax.lax.top_k ordering incl. ties; keys unique).
__global__ __launch_bounds__(256) void scan_kernel(const float* __restrict__ obj,
                                                   uint32_t* __restrict__ bcount,
                                                   unsigned long long* __restrict__ priv) {
    __shared__ uint32_t lcount;
    const int n = blockIdx.y, blk = blockIdx.x;
    const int tid = (int)threadIdx.x;
    if (tid == 0) lcount = 0;
    __syncthreads();
    const uint32_t T0 = f2sortable(2.60f);
    const float4* o4 = (const float4*)(obj + (size_t)n * A_ELEMS);
    unsigned long long* pv = priv + ((size_t)n * SBLK + blk) * BCAP2;
    const int n4 = A_ELEMS / 4;  // 125000, exact
    for (int i = blk * 256 + tid; i < n4; i += SBLK * 256) {
        float4 v = o4[i];
        uint32_t us[4] = {f2sortable(v.x), f2sortable(v.y), f2sortable(v.z), f2sortable(v.w)};
        #pragma unroll
        for (int c = 0; c < 4; ++c) {
            if (us[c] >= T0) {
                uint32_t pos = atomicAdd(&lcount, 1u);     // LDS atomic — cheap, rare
                if (pos < BCAP2) {
                    uint32_t idx = (uint32_t)(i * 4 + c);
                    pv[pos] = ((unsigned long long)us[c] << 32) |
                              (unsigned long long)(~idx);
                }
            }
        }
    }
    __syncthreads();
    if (tid == 0) bcount[(size_t)n * SBLK + blk] = lcount;   // uncapped (overflow check)
}

// ---------------- pass 2: validate; compact-copy — or exact fallback inline -------
// Normal path: prefix-sum 128 block counts, gather private lists into cand.
// Fallback (speculation failed, ~1e-11 for these inputs): same block rebuilds
// exactly via 2048-bin LDS histogram radix-select over all 500k scores.
__global__ __launch_bounds__(256) void check_kernel(
    const float* __restrict__ obj,
    const uint32_t* __restrict__ bcount,
    const unsigned long long* __restrict__ priv,
    uint32_t* __restrict__ cand_count, unsigned long long* __restrict__ cand) {
    __shared__ uint32_t cs[SBLK];
    __shared__ uint32_t ps[SBLK];
    __shared__ uint32_t pre[SBLK + 1];
    __shared__ uint32_t bad;
    const int n = blockIdx.x;
    const int tid = (int)threadIdx.x;
    if (tid == 0) bad = 0;
    __syncthreads();
    if (tid < SBLK) {
        uint32_t c = bcount[(size_t)n * SBLK + tid];
        cs[tid] = c; ps[tid] = c;
        if (c > BCAP2) atomicOr(&bad, 1u);   // overflowed block -> list incomplete
    }
    __syncthreads();
    for (int off = 1; off < SBLK; off <<= 1) {   // Hillis-Steele inclusive scan
        uint32_t v = 0;
        if (tid < SBLK) { v = ps[tid]; if (tid >= off) v += ps[tid - off]; }
        __syncthreads();
        if (tid < SBLK) ps[tid] = v;
        __syncthreads();
    }
    const uint32_t total = ps[SBLK - 1];
    if (tid < SBLK) pre[tid] = ps[tid] - cs[tid];
    if (tid == 0) pre[SBLK] = total;
    __syncthreads();
    unsigned long long* cn = cand + (size_t)n * CAP;
    if ((bad == 0) && (total >= TOPK) && (total <= CAP)) {
        // ---- normal path: gather private lists into contiguous cand[n][0..total)
        if (tid == 0) cand_count[n] = total;
        const unsigned long long* pv = priv + (size_t)n * SBLK * BCAP2;
        for (uint32_t g = tid; g < total; g += 256) {
            int lo = 0, hi = SBLK - 1;   // largest b with pre[b] <= g
            while (lo < hi) { int mid = (lo + hi + 1) >> 1; if (pre[mid] <= g) lo = mid; else hi = mid - 1; }
            cn[g] = pv[(size_t)lo * BCAP2 + (g - pre[lo])];
        }
    } else {
        // ---- exact fallback: full radix-select, one block, slow but never taken
        __shared__ uint32_t sh[NBINS];
        __shared__ uint32_t lcount;
        __shared__ uint32_t cutb;
        for (int i = tid; i < NBINS; i += 256) sh[i] = 0;
        if (tid == 0) lcount = 0;
        __syncthreads();
        const float* o = obj + (size_t)n * A_ELEMS;
        for (int i = tid; i < A_ELEMS; i += 256)
            atomicAdd(&sh[f2sortable(o[i]) >> 21], 1u);
        __syncthreads();
        if (tid == 0) {
            uint32_t cum = 0; int b;
            for (b = NBINS - 1; b > 0; --b) { cum += sh[b]; if (cum >= TOPK) break; }
            cutb = (uint32_t)b;
        }
        __syncthreads();
        const uint32_t cb = cutb;
        for (int i = tid; i < A_ELEMS; i += 256) {
            uint32_t u = f2sortable(o[i]);
            if ((u >> 21) >= cb) {
                uint32_t pos = atomicAdd(&lcount, 1u);
                if (pos < CAP)
                    cn[pos] = ((unsigned long long)u << 32) | (unsigned long long)(~(uint32_t)i);
            }
        }
        __syncthreads();
        if (tid == 0) cand_count[n] = lcount < CAP ? lcount : CAP;
    }
}

// ---------------- pass 3: partial ranks ----------------
// rank(t) = #{j : key_j > key_t}; keys unique -> rank == final sorted position.
// Block = (grp, seg, n): partial counts of its 1024 candidates (4 keys/thread
// in registers) against one 256-key segment in LDS; one broadcast ulonglong2
// read feeds 8 compares. Blocks beyond cnt exit immediately.
__global__ __launch_bounds__(256) void rank_partial_kernel(
    const uint32_t* __restrict__ cand_count,
    const unsigned long long* __restrict__ cand,
    uint16_t* __restrict__ partial) {
    __shared__ unsigned long long s[SEGK];   // 2 KB
    const int n = blockIdx.z, seg = blockIdx.y, grp = blockIdx.x;
    uint32_t cnt = cand_count[n];
    if (cnt > CAP) cnt = CAP;
    if ((uint32_t)(grp * 1024) >= cnt) return;   // dead candidate range
    if ((uint32_t)(seg * SEGK) >= cnt) return;   // empty key segment
    const unsigned long long* cn = cand + (size_t)n * CAP;
    const int ks = seg * SEGK;
    for (int i = threadIdx.x; i < SEGK; i += 256)
        s[i] = ((uint32_t)(ks + i) < cnt) ? cn[ks + i] : 0ull;  // pad 0 < any real key
    __syncthreads();
    const int t0 = grp * 1024 + (int)threadIdx.x;
    // keys for t >= cnt are garbage but their ranks are never consumed
    unsigned long long k0 = cn[t0], k1 = cn[t0 + 256], k2 = cn[t0 + 512], k3 = cn[t0 + 768];
    uint32_t r0 = 0, r1 = 0, r2 = 0, r3 = 0;
    const ulonglong2* s2 = (const ulonglong2*)s;
    #pragma unroll 8
    for (int j = 0; j < SEGK / 2; ++j) {
        ulonglong2 p = s2[j];                // wave-uniform broadcast read
        r0 += (p.x > k0); r0 += (p.y > k0);
        r1 += (p.x > k1); r1 += (p.y > k1);
        r2 += (p.x > k2); r2 += (p.y > k2);
        r3 += (p.x > k3); r3 += (p.y > k3);
    }
    uint16_t* pp = partial + ((size_t)n * SEG + seg) * CAP;
    pp[t0]       = (uint16_t)r0;
    pp[t0 + 256] = (uint16_t)r1;
    pp[t0 + 512] = (uint16_t)r2;
    pp[t0 + 768] = (uint16_t)r3;
}

// ---------------- pass 4: sum partials, gather, decode, write ----------------
__global__ __launch_bounds__(256) void decode_kernel(
    const float* __restrict__ anchors, const float* __restrict__ breg,
    const uint32_t* __restrict__ cand_count,
    const unsigned long long* __restrict__ cand,
    const uint16_t* __restrict__ partial,
    float* __restrict__ out) {
    const int n = blockIdx.y;
    const int t = blockIdx.x * 256 + (int)threadIdx.x;
    uint32_t cnt = cand_count[n];
    if (cnt > CAP) cnt = CAP;
    if ((uint32_t)t >= cnt) return;
    const int nseg = (int)((cnt + SEGK - 1) / SEGK);   // only written segments
    const uint16_t* pp = partial + (size_t)n * SEG * CAP;
    uint32_t rank = 0;
    for (int sg = 0; sg < nseg; ++sg) rank += pp[(size_t)sg * CAP + t];
    if (rank >= TOPK) return;
    const unsigned long long mykey = cand[(size_t)n * CAP + t];
    const uint32_t u    = (uint32_t)(mykey >> 32);
    const uint32_t idx  = ~((uint32_t)mykey);
    const uint32_t bits = (u & 0x80000000u) ? (u ^ 0x80000000u) : ~u;
    const float score = __uint_as_float(bits);
    const float4 a = ((const float4*)anchors)[(size_t)n * A_ELEMS + idx];
    const float4 b = ((const float4*)breg)[(size_t)n * A_ELEMS + idx];
    float w  = a.z - a.x + 1.0f;
    float h  = a.w - a.y + 1.0f;
    float cx = a.x + 0.5f * w;
    float cy = a.y + 0.5f * h;
    float dw = fminf(b.z, BBOX_CLIP);
    float dh = fminf(b.w, BBOX_CLIP);
    float pcx = b.x * w + cx;
    float pcy = b.y * h + cy;
    float pw  = expf(dw) * w;
    float ph  = expf(dh) * h;
    float* row = out + ((size_t)n * TOPK + rank) * 5;
    row[0] = pcx - 0.5f * pw;
    row[1] = pcy - 0.5f * ph;
    row[2] = pcx + 0.5f * pw - 1.0f;
    row[3] = pcy + 0.5f * ph - 1.0f;
    row[4] = score;
}

extern "C" void kernel_launch(void* const* d_in, const int* in_sizes, int n_in,
                              void* d_out, int out_size, void* d_ws, size_t ws_size,
                              hipStream_t stream) {
    const float* anchors    = (const float*)d_in[0];  // [8,500000,4]
    const float* objectness = (const float*)d_in[1];  // [8,500000,1]
    const float* breg       = (const float*)d_in[2];  // [8,500000,4]
    float* out = (float*)d_out;                        // [8,2000,5]

    // Workspace layout (every region written-before-read each call):
    //   [0,          4096)  bcount      uint32[8][128]
    //   [4096,    1052672)  priv        uint64[8][128][128]
    //   [1052672, 1052704)  cand_count  uint32[8]
    //   [1052736, 1577024)  cand        uint64[8][8192]
    //   [1577024, 5771328)  partial     uint16[8][32][8192]
    uint8_t* ws = (uint8_t*)d_ws;
    uint32_t* bcount     = (uint32_t*)ws;
    unsigned long long* priv = (unsigned long long*)(ws + 4096);
    uint32_t* cand_count = (uint32_t*)(ws + 1052672);
    unsigned long long* cand = (unsigned long long*)(ws + 1052736);
    uint16_t* partial    = (uint16_t*)(ws + 1577024);

    dim3 g1(SBLK, N_BATCH);
    scan_kernel<<<g1, 256, 0, stream>>>(objectness, bcount, priv);
    check_kernel<<<N_BATCH, 256, 0, stream>>>(objectness, bcount, priv, cand_count, cand);
    dim3 g2(GRP, SEG, N_BATCH);
    rank_partial_kernel<<<g2, 256, 0, stream>>>(cand_count, cand, partial);
    dim3 g3(CAP / 256, N_BATCH);
    decode_kernel<<<g3, 256, 0, stream>>>(anchors, breg, cand_count, cand, partial, out);
}